// Round 4
// baseline (322.316 us; speedup 1.0000x reference)
//
#include <hip/hip_runtime.h>
#include <math.h>
#include <stdint.h>

#define ROWS 4096
#define COLS 8192
#define KSEL 4096
#define NT 256
#define NWAVE (NT / 64)
#define PT (COLS / (4 * NT))   // float4s per thread = 8 (32 elements)
#define NBINS 1024             // bins over u in [0, 0.75); width 7.32e-4
#define WMAX 128               // window elems/row: mean ~6, P(>128) ~ 0
#define RANGE_HI 0.75f
#define LN2F 0.69314718056f

// u = z + gumbel is the (monotone) selection key; bulk classification by
// 1024-bin histogram of fast-u (hw v_log_f32 chain, err ~2e-6 near the cut,
// bin width 7.3e-4), exact per-op-fp32-rounded fp64 chain only for the ~6
// elements/row in bins B-1..B+1 (bitwise-proven vs numpy in rounds 1-3).
__device__ __forceinline__ int bin_of(float u) {
    int b = (int)(u * ((float)NBINS / RANGE_HI));
    b = b < 0 ? 0 : b;
    b = b > NBINS - 1 ? NBINS - 1 : b;
    return b;
}

// No min-waves hint: let the allocator use a large VGPR budget so the 16
// float4 staging loads + u[32] stay in registers (round 3's ",5" produced
// VGPR_Count=28 => ~2 loads in flight => 2.2 TB/s MLP ceiling).
__global__ __launch_bounds__(NT) void mask_topk_kernel(
    const float* __restrict__ z, const float* __restrict__ eps,
    float* __restrict__ out)
{
    __shared__ uint32_t hist[NWAVE][NBINS];   // 16 KB, one copy per wave
    __shared__ uint32_t wtot[NWAVE];
    __shared__ int      winIdx[WMAX];
    __shared__ uint32_t winSig[WMAX];
    __shared__ int      s_B, s_need2;
    __shared__ uint32_t s_SB, s_wcount;

    const int row  = blockIdx.x;
    const int tid  = threadIdx.x;
    const int lane = tid & 63;
    const int wave = tid >> 6;
    const size_t rbase = (size_t)row * COLS;

    for (int i = tid; i < NWAVE * NBINS; i += NT) ((uint32_t*)hist)[i] = 0;
    if (tid == 0) s_wcount = 0;

    // ---- pass 1a: issue ALL global loads up front (max MLP) ----
    const float4* z4 = (const float4*)(z + rbase);
    const float4* e4 = (const float4*)(eps + rbase);
    float4 zr[PT], er[PT];
#pragma unroll
    for (int it = 0; it < PT; ++it) {
        zr[it] = z4[it * NT + tid];
        er[it] = e4[it * NT + tid];
    }
    __syncthreads();   // hist zero-init visible before atomics

    // ---- pass 1b: compute u in place (zr becomes u) + per-wave histogram ----
#pragma unroll
    for (int it = 0; it < PT; ++it) {
        float zz[4] = {zr[it].x, zr[it].y, zr[it].z, zr[it].w};
        float ee[4] = {er[it].x, er[it].y, er[it].z, er[it].w};
        float uu[4];
#pragma unroll
        for (int j = 0; j < 4; ++j) {
            float l1 = __builtin_amdgcn_logf(ee[j]) * LN2F;   // ~log(eps) < 0
            float l2 = __builtin_amdgcn_logf(-l1) * LN2F;     // ~log(-log eps)
            uu[j] = zz[j] - l2;                               // u = z + gumbel
            atomicAdd(&hist[wave][bin_of(uu[j])], 1u);
        }
        zr[it].x = uu[0]; zr[it].y = uu[1]; zr[it].z = uu[2]; zr[it].w = uu[3];
    }
    __syncthreads();

    // ---- per-thread 4-bin totals + shuffle-based block suffix scan ----
    const int hb = tid * (NBINS / NT);                        // 4 bins/thread
    uint32_t h[NBINS / NT];
    uint32_t cs = 0;
#pragma unroll
    for (int i = 0; i < NBINS / NT; ++i) {
        uint32_t t = 0;
#pragma unroll
        for (int c = 0; c < NWAVE; ++c) t += hist[c][hb + i];
        h[i] = t;
        cs += t;
    }
    uint32_t v = cs;                                          // wave suffix scan
#pragma unroll
    for (int off = 1; off < 64; off <<= 1) {
        uint32_t t = __shfl_down(v, off, 64);
        if (lane + off < 64) v += t;
    }
    if (lane == 0) wtot[wave] = v;
    __syncthreads();
    uint32_t above = 0;
#pragma unroll
    for (int c = 0; c < NWAVE; ++c) above += (c > wave) ? wtot[c] : 0u;
    uint32_t cum = (v + above) - cs;   // count in bins above my 4-bin chunk

    for (int i = NBINS / NT - 1; i >= 0; --i) {               // unique writer
        if (cum < KSEL && KSEL <= cum + h[i]) { s_B = hb + i; s_SB = cum; }
        cum += h[i];
    }
    __syncthreads();
    const int B = s_B;
    if (tid == 0) {
        uint32_t hB1 = 0;
        if (B + 1 < NBINS)
            for (int c = 0; c < NWAVE; ++c) hB1 += hist[c][B + 1];
        s_need2 = KSEL - (int)(s_SB - hB1);   // K minus certain-1s (bins > B+1)
    }
    __syncthreads();
    const int need2 = s_need2;

    // ---- pass 2: classify from registers, write, collect window ----
    float4* o4 = (float4*)(out + rbase);
#pragma unroll
    for (int it = 0; it < PT; ++it) {
        const int k = it * NT + tid;
        float uu[4] = {zr[it].x, zr[it].y, zr[it].z, zr[it].w};
        float oo[4];
#pragma unroll
        for (int j = 0; j < 4; ++j) {
            int b = bin_of(uu[j]);
            oo[j] = (b > B + 1) ? 1.0f : 0.0f;
            if (b >= B - 1 && b <= B + 1) {
                uint32_t slot = atomicAdd(&s_wcount, 1u);
                if (slot < WMAX) winIdx[slot] = k * 4 + j;
            }
        }
        float4 ov; ov.x = oo[0]; ov.y = oo[1]; ov.z = oo[2]; ov.w = oo[3];
        o4[k] = ov;
    }
    __syncthreads();

    // ---- resolve window with exact per-op-fp32-rounded chain ----
    int w = (int)s_wcount; if (w > WMAX) w = WMAX;
    if (tid < 64) {
        for (int j = lane; j < w; j += 64) {
            int idx = winIdx[j];
            float e  = eps[rbase + idx];
            float zz = z[rbase + idx];
            float l1  = (float)log((double)e);
            float l2  = (float)log((double)(-l1));
            float g   = -l2;
            float s   = zz + g;
            float t   = s / (2.0f / 3.0f);
            float ex  = (float)exp(-(double)t);
            float sig = 1.0f / (1.0f + ex);
            winSig[j] = __float_as_uint(sig);   // sig in (0,1): uint order = float order
        }
    }
    __syncthreads();
    if (tid < 64) {
        for (int j = lane; j < w; j += 64) {
            uint32_t sj = winSig[j];
            int ij = winIdx[j];
            int rank = 0;
            for (int kk = 0; kk < w; ++kk) {
                uint32_t sk = winSig[kk];
                int ik = winIdx[kk];
                rank += (sk > sj || (sk == sj && ik < ij)) ? 1 : 0;
            }
            out[rbase + ij] = (rank < need2) ? 1.0f : 0.0f;
        }
    }
}

extern "C" void kernel_launch(void* const* d_in, const int* in_sizes, int n_in,
                              void* d_out, int out_size, void* d_ws, size_t ws_size,
                              hipStream_t stream) {
    const float* z   = (const float*)d_in[0];
    const float* eps = (const float*)d_in[1];
    float* out = (float*)d_out;
    hipLaunchKernelGGL(mask_topk_kernel, dim3(ROWS), dim3(NT), 0, stream,
                       z, eps, out);
}

// Round 5
// 318.789 us; speedup vs baseline: 1.0111x; 1.0111x over previous
//
#include <hip/hip_runtime.h>
#include <math.h>
#include <stdint.h>

#define ROWS 4096
#define COLS 8192
#define KSEL 4096
#define NT 256
#define NWAVE (NT / 64)
#define PT (COLS / (4 * NT))   // float4s per thread = 8 (32 elements)
#define NBINS 1024             // bins over u in [0, 0.75); width 7.32e-4
#define WMAX 128               // window elems/row: mean ~6, P(>128) ~ 0
#define RANGE_HI 0.75f
#define LN2F 0.69314718056f

// u = z + gumbel is the (monotone) selection key; bulk classification by
// 1024-bin histogram of fast-u (hw v_log_f32 chain, err ~2e-6 near the cut,
// bin width 7.3e-4), exact per-op-fp32-rounded fp64 chain only for the ~6
// elements/row in bins B-1..B+1 (bitwise-proven vs numpy in rounds 1-4).
__device__ __forceinline__ int bin_of(float u) {
    int b = (int)(u * ((float)NBINS / RANGE_HI));
    b = b < 0 ? 0 : b;
    b = b > NBINS - 1 ? NBINS - 1 : b;
    return b;
}

__global__ __launch_bounds__(NT) void mask_topk_kernel(
    const float* __restrict__ z, const float* __restrict__ eps,
    float* __restrict__ out)
{
    __shared__ uint32_t hist[NWAVE][NBINS];   // 16 KB, one copy per wave
    __shared__ uint32_t wtot[NWAVE];
    __shared__ int      winIdx[WMAX];
    __shared__ uint32_t winSig[WMAX];
    __shared__ int      s_B, s_need2;
    __shared__ uint32_t s_SB, s_wcount;

    const int row  = blockIdx.x;
    const int tid  = threadIdx.x;
    const int lane = tid & 63;
    const int wave = tid >> 6;
    const size_t rbase = (size_t)row * COLS;

    // ---- pass 1a: issue ALL 16 global loads FIRST (max MLP) ----
    const float4* z4 = (const float4*)(z + rbase);
    const float4* e4 = (const float4*)(eps + rbase);
    float4 zr[PT], er[PT];
#pragma unroll
    for (int it = 0; it < PT; ++it) {
        zr[it] = z4[it * NT + tid];
        er[it] = e4[it * NT + tid];
    }
    // Pin the scheduler: round 4's VGPR_Count=36 proved LLVM sinks these
    // loads into the compute loop (=> ~2 outstanding loads/wave => 2.2 TB/s
    // Little's-law ceiling). Nothing may cross this point.
    __builtin_amdgcn_sched_barrier(0);

    // hist zero-init overlaps the in-flight loads
    for (int i = tid; i < NWAVE * NBINS; i += NT) ((uint32_t*)hist)[i] = 0;
    if (tid == 0) s_wcount = 0;
    __syncthreads();

    // ---- pass 1b: compute u in place (zr becomes u) + per-wave histogram ----
#pragma unroll
    for (int it = 0; it < PT; ++it) {
        float zz[4] = {zr[it].x, zr[it].y, zr[it].z, zr[it].w};
        float ee[4] = {er[it].x, er[it].y, er[it].z, er[it].w};
        float uu[4];
#pragma unroll
        for (int j = 0; j < 4; ++j) {
            float l1 = __builtin_amdgcn_logf(ee[j]) * LN2F;   // ~log(eps) < 0
            float l2 = __builtin_amdgcn_logf(-l1) * LN2F;     // ~log(-log eps)
            uu[j] = zz[j] - l2;                               // u = z + gumbel
            atomicAdd(&hist[wave][bin_of(uu[j])], 1u);
        }
        zr[it].x = uu[0]; zr[it].y = uu[1]; zr[it].z = uu[2]; zr[it].w = uu[3];
    }
    __syncthreads();

    // ---- per-thread 4-bin totals + shuffle-based block suffix scan ----
    const int hb = tid * (NBINS / NT);                        // 4 bins/thread
    uint32_t h[NBINS / NT];
    uint32_t cs = 0;
#pragma unroll
    for (int i = 0; i < NBINS / NT; ++i) {
        uint32_t t = 0;
#pragma unroll
        for (int c = 0; c < NWAVE; ++c) t += hist[c][hb + i];
        h[i] = t;
        cs += t;
    }
    uint32_t v = cs;                                          // wave suffix scan
#pragma unroll
    for (int off = 1; off < 64; off <<= 1) {
        uint32_t t = __shfl_down(v, off, 64);
        if (lane + off < 64) v += t;
    }
    if (lane == 0) wtot[wave] = v;
    __syncthreads();
    uint32_t above = 0;
#pragma unroll
    for (int c = 0; c < NWAVE; ++c) above += (c > wave) ? wtot[c] : 0u;
    uint32_t cum = (v + above) - cs;   // count in bins above my 4-bin chunk

    for (int i = NBINS / NT - 1; i >= 0; --i) {               // unique writer
        if (cum < KSEL && KSEL <= cum + h[i]) { s_B = hb + i; s_SB = cum; }
        cum += h[i];
    }
    __syncthreads();
    const int B = s_B;
    if (tid == 0) {
        uint32_t hB1 = 0;
        if (B + 1 < NBINS)
            for (int c = 0; c < NWAVE; ++c) hB1 += hist[c][B + 1];
        s_need2 = KSEL - (int)(s_SB - hB1);   // K minus certain-1s (bins > B+1)
    }
    __syncthreads();
    const int need2 = s_need2;

    // ---- pass 2: classify from registers, write, collect window ----
    float4* o4 = (float4*)(out + rbase);
#pragma unroll
    for (int it = 0; it < PT; ++it) {
        const int k = it * NT + tid;
        float uu[4] = {zr[it].x, zr[it].y, zr[it].z, zr[it].w};
        float oo[4];
#pragma unroll
        for (int j = 0; j < 4; ++j) {
            int b = bin_of(uu[j]);
            oo[j] = (b > B + 1) ? 1.0f : 0.0f;
            if (b >= B - 1 && b <= B + 1) {
                uint32_t slot = atomicAdd(&s_wcount, 1u);
                if (slot < WMAX) winIdx[slot] = k * 4 + j;
            }
        }
        float4 ov; ov.x = oo[0]; ov.y = oo[1]; ov.z = oo[2]; ov.w = oo[3];
        o4[k] = ov;
    }
    __syncthreads();

    // ---- resolve window with exact per-op-fp32-rounded chain ----
    int w = (int)s_wcount; if (w > WMAX) w = WMAX;
    if (tid < 64) {
        for (int j = lane; j < w; j += 64) {
            int idx = winIdx[j];
            float e  = eps[rbase + idx];
            float zz = z[rbase + idx];
            float l1  = (float)log((double)e);
            float l2  = (float)log((double)(-l1));
            float g   = -l2;
            float s   = zz + g;
            float t   = s / (2.0f / 3.0f);
            float ex  = (float)exp(-(double)t);
            float sig = 1.0f / (1.0f + ex);
            winSig[j] = __float_as_uint(sig);   // sig in (0,1): uint order = float order
        }
    }
    __syncthreads();
    if (tid < 64) {
        for (int j = lane; j < w; j += 64) {
            uint32_t sj = winSig[j];
            int ij = winIdx[j];
            int rank = 0;
            for (int kk = 0; kk < w; ++kk) {
                uint32_t sk = winSig[kk];
                int ik = winIdx[kk];
                rank += (sk > sj || (sk == sj && ik < ij)) ? 1 : 0;
            }
            out[rbase + ij] = (rank < need2) ? 1.0f : 0.0f;
        }
    }
}

extern "C" void kernel_launch(void* const* d_in, const int* in_sizes, int n_in,
                              void* d_out, int out_size, void* d_ws, size_t ws_size,
                              hipStream_t stream) {
    const float* z   = (const float*)d_in[0];
    const float* eps = (const float*)d_in[1];
    float* out = (float*)d_out;
    hipLaunchKernelGGL(mask_topk_kernel, dim3(ROWS), dim3(NT), 0, stream,
                       z, eps, out);
}